// Round 3
// baseline (55.704 us; speedup 1.0000x reference)
//
#include <hip/hip_runtime.h>

// QProduct: out_real/out_imag[b,s, j0*1024 + j1*32 + j2] =
//   ((1+1i) * h0[j0] * h1[j1] * h2[j2]) split into real/imag.
// B=8, S=128, d=32. Output: two (B,S,32768) fp32 tensors concatenated.
// Memory-bound on 268 MB of streaming writes -> nontemporal stores.

#define BS_TOTAL 1024           // B*S
#define D 32
#define OUT_PER_BS 32768        // 32*32*32
#define IMAG_OFF ((long long)BS_TOTAL * OUT_PER_BS)

typedef float f32x4 __attribute__((ext_vector_type(4)));

__global__ __launch_bounds__(256) void qproduct_kernel(
    const float* __restrict__ h0r, const float* __restrict__ h0i,
    const float* __restrict__ h1r, const float* __restrict__ h1i,
    const float* __restrict__ h2r, const float* __restrict__ h2i,
    float* __restrict__ out)
{
    const int bs  = blockIdx.x;      // 0..1023  (b*S + s)
    const int tid = threadIdx.x;     // 0..255

    __shared__ float s_h0r[D];
    __shared__ float s_h0i[D];

    const int base = bs * D;
    if (tid < D) {
        s_h0r[tid] = h0r[base + tid];
        s_h0i[tid] = h0i[base + tid];
    }
    __syncthreads();

    // Thread owns (j1, j2 quad): tid = j1*8 + (j2/4)
    const int j1  = tid >> 3;         // 0..31
    const int j2b = (tid & 7) << 2;   // 0,4,...,28

    const float b1r = h1r[base + j1];
    const float b1i = h1i[base + j1];
    const f32x4 c2r = *reinterpret_cast<const f32x4*>(h2r + base + j2b);
    const f32x4 c2i = *reinterpret_cast<const f32x4*>(h2i + base + j2b);

    float* __restrict__ outR = out + (long long)bs * OUT_PER_BS + (tid << 2);
    float* __restrict__ outI = outR + IMAG_OFF;

    #pragma unroll
    for (int j0 = 0; j0 < D; ++j0) {
        const float a0r = s_h0r[j0];
        const float a0i = s_h0i[j0];
        // t1 = (1 + 1i) * h0[j0]   (reference inits BOTH tp_real and tp_imag to 1)
        const float t1r = a0r - a0i;
        const float t1i = a0r + a0i;
        // t2 = t1 * h1[j1]
        const float t2r = t1r * b1r - t1i * b1i;
        const float t2i = t1r * b1i + t1i * b1r;
        // out = t2 * h2[j2..j2+3]
        f32x4 vr, vi;
        vr = t2r * c2r - t2i * c2i;
        vi = t2r * c2i + t2i * c2r;

        __builtin_nontemporal_store(vr, reinterpret_cast<f32x4*>(outR + j0 * 1024));
        __builtin_nontemporal_store(vi, reinterpret_cast<f32x4*>(outI + j0 * 1024));
    }
}

extern "C" void kernel_launch(void* const* d_in, const int* in_sizes, int n_in,
                              void* d_out, int out_size, void* d_ws, size_t ws_size,
                              hipStream_t stream) {
    const float* h0r = (const float*)d_in[0];
    const float* h0i = (const float*)d_in[1];
    const float* h1r = (const float*)d_in[2];
    const float* h1i = (const float*)d_in[3];
    const float* h2r = (const float*)d_in[4];
    const float* h2i = (const float*)d_in[5];
    float* out = (float*)d_out;

    qproduct_kernel<<<BS_TOTAL, 256, 0, stream>>>(h0r, h0i, h1r, h1i, h2r, h2i, out);
}

// Round 4
// 44.772 us; speedup vs baseline: 1.2442x; 1.2442x over previous
//
#include <hip/hip_runtime.h>

// QProduct: out_real/out_imag[b,s, j0*1024 + j1*32 + j2] =
//   ((1+1i) * h0[j0] * h1[j1] * h2[j2]) split into real/imag.
// B=8, S=128, d=32. Output: two (B,S,32768) fp32 tensors concatenated.
// Memory-bound on 268 MB of streaming writes. Plain stores (NT regressed -24%).
// 512 threads/block: tid<256 writes real plane, tid>=256 writes imag plane,
// so each wave emits a single sequential store stream.

#define BS_TOTAL 1024           // B*S
#define D 32
#define OUT_PER_BS 32768        // 32*32*32
#define IMAG_OFF ((long long)BS_TOTAL * OUT_PER_BS)

typedef float f32x4 __attribute__((ext_vector_type(4)));

__global__ __launch_bounds__(512) void qproduct_kernel(
    const float* __restrict__ h0r, const float* __restrict__ h0i,
    const float* __restrict__ h1r, const float* __restrict__ h1i,
    const float* __restrict__ h2r, const float* __restrict__ h2i,
    float* __restrict__ out)
{
    const int bs   = blockIdx.x;          // 0..1023  (b*S + s)
    const int tid  = threadIdx.x & 255;   // position within plane
    const int plane = threadIdx.x >> 8;   // 0 = real, 1 = imag

    __shared__ float s_h0r[D];
    __shared__ float s_h0i[D];

    const int base = bs * D;
    if (threadIdx.x < D) {
        s_h0r[threadIdx.x] = h0r[base + threadIdx.x];
        s_h0i[threadIdx.x] = h0i[base + threadIdx.x];
    }
    __syncthreads();

    // Thread owns (j1, j2 quad): tid = j1*8 + (j2/4)
    const int j1  = tid >> 3;         // 0..31
    const int j2b = (tid & 7) << 2;   // 0,4,...,28

    const float b1r = h1r[base + j1];
    const float b1i = h1i[base + j1];
    const f32x4 c2r = *reinterpret_cast<const f32x4*>(h2r + base + j2b);
    const f32x4 c2i = *reinterpret_cast<const f32x4*>(h2i + base + j2b);

    float* __restrict__ outP = out + (long long)bs * OUT_PER_BS + (tid << 2)
                             + (plane ? IMAG_OFF : 0);

    #pragma unroll
    for (int j0 = 0; j0 < D; ++j0) {
        const float a0r = s_h0r[j0];
        const float a0i = s_h0i[j0];
        // t1 = (1 + 1i) * h0[j0]   (reference inits BOTH tp_real and tp_imag to 1)
        const float t1r = a0r - a0i;
        const float t1i = a0r + a0i;
        // t2 = t1 * h1[j1]
        const float t2r = t1r * b1r - t1i * b1i;
        const float t2i = t1r * b1i + t1i * b1r;
        // out = t2 * h2[j2..j2+3]  — real or imag component per plane
        f32x4 v;
        if (plane == 0) v = t2r * c2r - t2i * c2i;
        else            v = t2r * c2i + t2i * c2r;

        *reinterpret_cast<f32x4*>(outP + j0 * 1024) = v;
    }
}

extern "C" void kernel_launch(void* const* d_in, const int* in_sizes, int n_in,
                              void* d_out, int out_size, void* d_ws, size_t ws_size,
                              hipStream_t stream) {
    const float* h0r = (const float*)d_in[0];
    const float* h0i = (const float*)d_in[1];
    const float* h1r = (const float*)d_in[2];
    const float* h1i = (const float*)d_in[3];
    const float* h2r = (const float*)d_in[4];
    const float* h2i = (const float*)d_in[5];
    float* out = (float*)d_out;

    qproduct_kernel<<<BS_TOTAL, 512, 0, stream>>>(h0r, h0i, h1r, h1i, h2r, h2i, out);
}